// Round 11
// baseline (1219.629 us; speedup 1.0000x reference)
//
#include <hip/hip_runtime.h>

#define BT     32768
#define HIDDEN 512
#define DDIM   256
#define KCODE  1024
#define NQUANT 8

typedef _Float16 f16;
typedef _Float16 f16x8 __attribute__((ext_vector_type(8)));
typedef float f32x4 __attribute__((ext_vector_type(4)));
typedef float f32x8 __attribute__((ext_vector_type(8)));

#define LO_SCALE 64.0f
#define LO_INV   0.015625f

// ---------------------------------------------------------------------------
// cnorm: ||c||^2 for all NQ*K codes (fp32 exact)
// ---------------------------------------------------------------------------
__global__ __launch_bounds__(256) void cnorm_kernel(const float* __restrict__ cb,
                                                    float* __restrict__ cnorm) {
  __shared__ float red[256];
  const int code = blockIdx.x;
  const float v = cb[(size_t)code * DDIM + threadIdx.x];
  red[threadIdx.x] = v * v;
  __syncthreads();
  for (int s = 128; s > 0; s >>= 1) {
    if (threadIdx.x < s) red[threadIdx.x] += red[threadIdx.x + s];
    __syncthreads();
  }
  if (threadIdx.x == 0) cnorm[code] = red[0];
}

// ---------------------------------------------------------------------------
// codebooks -> f16 hi/lo ext: cbext[c][0..255]=hi, [256..511]=lo*64
// ---------------------------------------------------------------------------
__global__ __launch_bounds__(256) void cbext_conv(const float* __restrict__ cb,
                                                  f16* __restrict__ cbext) {
  const size_t idx = (size_t)blockIdx.x * 256 + threadIdx.x;
  const size_t c = idx >> 8;
  const int d = (int)(idx & 255);
  const float v = cb[idx];
  const f16 hi = (f16)v;
  cbext[c * 512 + d] = hi;
  cbext[c * 512 + 256 + d] = (f16)((v - (float)hi) * LO_SCALE);
}

// ---------------------------------------------------------------------------
// weight -> f16 hi/lo ext: Wext[n][0..K-1]=hi, [K..2K-1]=lo*64
// ---------------------------------------------------------------------------
__global__ __launch_bounds__(256) void bext_conv(const float* __restrict__ W,
                                                 f16* __restrict__ Wext,
                                                 int N, int K) {
  const int idx = blockIdx.x * 256 + threadIdx.x;
  if (idx >= N * K) return;
  const int n = idx / K, k = idx - n * K;
  const float v = W[idx];
  const f16 hi = (f16)v;
  Wext[(size_t)n * 2 * K + k] = hi;
  Wext[(size_t)n * 2 * K + K + k] = (f16)((v - (float)hi) * LO_SCALE);
}

__global__ void zero2(float* commitAcc, unsigned* bar) {
  commitAcc[0] = 0.f;
  bar[0] = 0u;
}

__global__ void finalize_com(const float* __restrict__ a, float* __restrict__ o) {
  o[0] = a[0] * (1.0f / (float)((size_t)NQUANT * BT * DDIM));
}

// ---------------------------------------------------------------------------
// Bounded-spin grid phase barrier (cache-phasing only; timeout-safe).
// ---------------------------------------------------------------------------
__device__ __forceinline__ void phase_barrier(unsigned* bar, unsigned gen,
                                              unsigned nblk) {
  __syncthreads();
  if (threadIdx.x == 0) {
    __threadfence();
    atomicAdd(bar, 1u);
    const unsigned target = gen * nblk;
    int spins = 0;
    while (__hip_atomic_load(bar, __ATOMIC_RELAXED, __HIP_MEMORY_SCOPE_AGENT) < target &&
           spins < 16384) {
      ++spins;
      __builtin_amdgcn_s_sleep(4);
    }
  }
  __syncthreads();
}

// ---------------------------------------------------------------------------
// Fused 8-step RVQ, M=32/wave (B-fragment reuse halves LDS reads vs R9).
// R6 structure (bench-validated correctness) + amdgpu_waves_per_eu(2,2) so
// the allocator budgets 256 VGPRs/lane (2 waves/SIMD; LDS pins 1 block/CU):
// af[2][16] (128 VGPR) + bf + acc + argmin ~ 225 regs, no spill expected.
// Waves = 4 token-groups (wr) x 2 code-halves (wc); wave owns 32 tokens,
// sweeps its 512-code half in 16 chunks of 32 codes. B staged global->LDS
// (global_load_lds w16, XOR swizzle byte^=(row&7)<<4 both sides), dbuf.
// Per chunk: t0-3 hi_r*lo_c, t4-7 lo_r*hi_c, *=1/64, t8-11 hi_r*hi_c.
// Builtin MFMA only (inline-asm MFMA = R8 NaN: hazard nops skipped).
// ---------------------------------------------------------------------------
__global__ __launch_bounds__(512)
__attribute__((amdgpu_waves_per_eu(2, 2)))
void rvq_fused7(
    const f16* __restrict__ rext, const f16* __restrict__ cbext,
    const float* __restrict__ cbf32, const float* __restrict__ cnorm,
    float* __restrict__ qsum, float* __restrict__ q1, float* __restrict__ q2,
    float* __restrict__ commitAcc, unsigned* __restrict__ bar) {
  __shared__ __align__(16) f16 Bs[2][64][512];   // 128 KB (2 halves x 32 rows, dbuf)
  __shared__ float mv[2][128];
  __shared__ int   mi[2][128];
  __shared__ int   bidx[128];
  __shared__ float redc[512];
  const int tid = threadIdx.x;
  const int w = tid >> 6, l = tid & 63;
  const int wr = w >> 1, wc = w & 1;
  const int lj = l & 15, li = l >> 4;
  const int m0 = blockIdx.x * 128;
  const int key = (lj & 7) << 4;                 // read-side swizzle key

  f16x8 af[2][16];
#pragma unroll
  for (int m = 0; m < 2; ++m) {
    const int row = m0 + wr * 32 + m * 16 + lj;
#pragma unroll
    for (int s = 0; s < 16; ++s)
      af[m][s] = *(const f16x8*)&rext[(size_t)row * 512 + s * 32 + li * 8];
  }

  float csum = 0.f;

#pragma unroll 1
  for (int nq = 0; nq < NQUANT; ++nq) {
    if (nq > 0) phase_barrier(bar, (unsigned)nq, gridDim.x);
    const f16* cbq = cbext + (size_t)nq * KCODE * 512;
    const float* cnq = cnorm + nq * KCODE;

    // stage chunk: row r (0..63) -> half h=r>>5, code h*512+chunk*32+(r&31)
    auto STAGE = [&](int chunk, int buf) {
#pragma unroll
      for (int q = 0; q < 8; ++q) {
        const int r = w * 8 + q;
        const int code = (r >> 5) * 512 + chunk * 32 + (r & 31);
        const char* src = (const char*)(cbq + ((size_t)code << 9)) +
                          ((l * 16) ^ ((r & 7) << 4));
        __builtin_amdgcn_global_load_lds(
            (const __attribute__((address_space(1))) void*)src,
            (__attribute__((address_space(3))) void*)&Bs[buf][r][0], 16, 0, 0);
      }
    };

    float bval[2][4]; int bidxr[2][4];
#pragma unroll
    for (int m = 0; m < 2; ++m)
#pragma unroll
      for (int j = 0; j < 4; ++j) { bval[m][j] = 3.0e38f; bidxr[m][j] = 0; }

    STAGE(0, 0);
    __syncthreads();
    int buf = 0;

#pragma unroll 1
    for (int c = 0; c < 16; ++c) {
      if (c < 15) STAGE(c + 1, buf ^ 1);
      f32x4 acc[2][2];
#pragma unroll
      for (int m = 0; m < 2; ++m)
#pragma unroll
        for (int n = 0; n < 2; ++n) acc[m][n] = (f32x4){0.f, 0.f, 0.f, 0.f};

#pragma unroll
      for (int t = 0; t < 12; ++t) {
        const int tl = (t < 4) ? t : (t < 8 ? t - 4 : t - 8);
        const int roff = (t < 4) ? 512 : 0;      // lo_c | hi_c | hi_c
        const int abase = (t >= 4 && t < 8) ? (8 + 2 * tl) : (2 * tl);
#pragma unroll
        for (int n = 0; n < 2; ++n) {
          const int rr = wc * 32 + n * 16 + lj;
          f16x8 bf[2];
#pragma unroll
          for (int kk = 0; kk < 2; ++kk) {
            const int boff = roff + tl * 128 + kk * 64 + li * 16;
            bf[kk] = *(const f16x8*)((const char*)&Bs[buf][rr][0] + (boff ^ key));
          }
#pragma unroll
          for (int m = 0; m < 2; ++m)
#pragma unroll
            for (int kk = 0; kk < 2; ++kk)
              acc[m][n] = __builtin_amdgcn_mfma_f32_16x16x32_f16(
                  af[m][abase + kk], bf[kk], acc[m][n], 0, 0, 0);
        }
        if (t == 7) {
#pragma unroll
          for (int m = 0; m < 2; ++m)
#pragma unroll
            for (int n = 0; n < 2; ++n)
#pragma unroll
              for (int j = 0; j < 4; ++j) acc[m][n][j] *= LO_INV;
        }
      }
      // distances + running argmin (ascending order -> first-occurrence)
#pragma unroll
      for (int n = 0; n < 2; ++n) {
        const int cl = wc * 512 + c * 32 + n * 16 + lj;
        const float cn = cnq[cl];
#pragma unroll
        for (int m = 0; m < 2; ++m)
#pragma unroll
          for (int j = 0; j < 4; ++j) {
            const float d = cn - 2.0f * acc[m][n][j];
            if (d < bval[m][j]) { bval[m][j] = d; bidxr[m][j] = cl; }
          }
      }
      __syncthreads();                           // staging + buf reads done
      buf ^= 1;
    }

    // reduce over the 16-lane code axis (lexicographic (val, idx) min)
#pragma unroll
    for (int off = 1; off < 16; off <<= 1) {
#pragma unroll
      for (int m = 0; m < 2; ++m)
#pragma unroll
        for (int j = 0; j < 4; ++j) {
          const float ov = __shfl_xor(bval[m][j], off);
          const int oi = __shfl_xor(bidxr[m][j], off);
          if (ov < bval[m][j] || (ov == bval[m][j] && oi < bidxr[m][j])) {
            bval[m][j] = ov; bidxr[m][j] = oi;
          }
        }
    }
    if (lj == 0) {
#pragma unroll
      for (int m = 0; m < 2; ++m)
#pragma unroll
        for (int j = 0; j < 4; ++j) {
          const int tok = wr * 32 + m * 16 + li * 4 + j;
          mv[wc][tok] = bval[m][j]; mi[wc][tok] = bidxr[m][j];
        }
    }
    __syncthreads();
    if (tid < 128) {                             // wc0 codes < wc1 codes
      float v0 = mv[0][tid]; int i0 = mi[0][tid];
      if (mv[1][tid] < v0) { v0 = mv[1][tid]; i0 = mi[1][tid]; }
      bidx[tid] = i0;
    }
    __syncthreads();

    // in-register residual update (both wc copies) + q1/q2 (wc==0 only)
#pragma unroll
    for (int m = 0; m < 2; ++m) {
      const int tokl = wr * 32 + m * 16 + lj;
      const int code = bidx[tokl];
      const float* qrow = cbf32 + ((size_t)nq * KCODE + code) * DDIM;
#pragma unroll
      for (int s = 0; s < 8; ++s) {
        const f32x8 qv = *(const f32x8*)&qrow[s * 32 + li * 8];
        f16x8 h = af[m][s], lo = af[m][8 + s];
#pragma unroll
        for (int i = 0; i < 8; ++i) {
          const float rold = (float)h[i] + (float)lo[i] * LO_INV;
          const float diff = qv[i] - rold;
          if (wc == 0) csum += diff * diff;
          const float rnew = rold - qv[i];
          const f16 nh = (f16)rnew;
          h[i] = nh;
          lo[i] = (f16)((rnew - (float)nh) * LO_SCALE);
        }
        af[m][s] = h; af[m][8 + s] = lo;
        if (wc == 0 && nq == 0)
          *(f32x8*)&q1[(size_t)(m0 + tokl) * DDIM + s * 32 + li * 8] = qv;
        if (wc == 0 && nq == 1)
          *(f32x8*)&q2[(size_t)(m0 + tokl) * DDIM + s * 32 + li * 8] = qv;
      }
    }
    __syncthreads();                             // protect mv/mi/bidx
  }

  // qsum = h - r_final (h re-read from untouched rext); wc==0 writes
  if (wc == 0) {
#pragma unroll
    for (int m = 0; m < 2; ++m) {
      const int row = m0 + wr * 32 + m * 16 + lj;
#pragma unroll
      for (int s = 0; s < 8; ++s) {
        const f16x8 hh = *(const f16x8*)&rext[(size_t)row * 512 + s * 32 + li * 8];
        const f16x8 hl = *(const f16x8*)&rext[(size_t)row * 512 + 256 + s * 32 + li * 8];
        f32x8 o;
#pragma unroll
        for (int i = 0; i < 8; ++i)
          o[i] = ((float)hh[i] + (float)hl[i] * LO_INV) -
                 ((float)af[m][s][i] + (float)af[m][8 + s][i] * LO_INV);
        *(f32x8*)&qsum[(size_t)row * DDIM + s * 32 + li * 8] = o;
      }
    }
  }

  redc[tid] = csum;
  __syncthreads();
  for (int s = 256; s > 0; s >>= 1) {
    if (tid < s) redc[tid] += redc[tid + s];
    __syncthreads();
  }
  if (tid == 0) atomicAdd(commitAcc, redc[0]);
}

// ---------------------------------------------------------------------------
// Projection v3 (builtin MFMA — R9-bench-passing version, unchanged).
// Block = 128 tokens x 128 cols, 8 waves x 16 tokens; B panel in LDS.
// ---------------------------------------------------------------------------
template <int K, bool WEXT>
__global__ __launch_bounds__(512) void proj3(
    const float* __restrict__ A, const f16* __restrict__ Bext,
    const float* __restrict__ bias, float* __restrict__ Cout,
    f16* __restrict__ CextOut, int Ntot) {
  __shared__ __align__(16) f16 Bs[128][512];     // 128 KB
  const int tid = threadIdx.x;
  const int w = tid >> 6, l = tid & 63;
  const int lj = l & 15, li = l >> 4;
  const int m0 = blockIdx.x * 128;
  const int n0 = blockIdx.y * 128;
  const int row_t = m0 + w * 16 + lj;
  const int key = (lj & 7) << 4;

  f32x4 acc[8], acc2[8];
#pragma unroll
  for (int n = 0; n < 8; ++n) {
    acc[n] = (f32x4){0.f, 0.f, 0.f, 0.f};
    acc2[n] = (f32x4){0.f, 0.f, 0.f, 0.f};
  }

#pragma unroll 1
  for (int p = 0; p < K / 256; ++p) {
    __syncthreads();
#pragma unroll
    for (int q = 0; q < 16; ++q) {
      const int r = w * 16 + q;
      const int nrow = n0 + r;
      const int byteoff = (l * 16) ^ ((r & 7) << 4);
      const char* hi_base =
          (const char*)Bext + ((size_t)nrow * 2 * K + p * 256) * 2;
      const char* lo_base =
          (const char*)Bext + ((size_t)nrow * 2 * K + K + p * 256) * 2;
      const char* src = (byteoff < 512) ? hi_base + byteoff
                                        : lo_base + (byteoff - 512);
      __builtin_amdgcn_global_load_lds(
          (const __attribute__((address_space(1))) void*)src,
          (__attribute__((address_space(3))) void*)&Bs[r][0], 16, 0, 0);
    }
    f16x8 ahi[8], alo[8];
#pragma unroll
    for (int s = 0; s < 8; ++s) {
      const f32x8 v = *(const f32x8*)&A[(size_t)row_t * K + p * 256 + s * 32 + li * 8];
      f16x8 h, lo;
#pragma unroll
      for (int i = 0; i < 8; ++i) {
        const f16 hh = (f16)v[i];
        h[i] = hh;
        lo[i] = (f16)((v[i] - (float)hh) * LO_SCALE);
      }
      ahi[s] = h; alo[s] = lo;
    }
    __syncthreads();

#pragma unroll
    for (int t = 0; t < 12; ++t) {
      const int tl = (t < 4) ? t : (t < 8 ? t - 4 : t - 8);
      const int roff = (t < 4) ? 512 : 0;
#pragma unroll
      for (int n = 0; n < 8; ++n) {
        const int rr = n * 16 + lj;
#pragma unroll
        for (int kk = 0; kk < 2; ++kk) {
          const int boff = roff + tl * 128 + kk * 64 + li * 16;
          const f16x8 bf = *(const f16x8*)((const char*)&Bs[rr][0] + (boff ^ key));
          if (t < 4)
            acc2[n] = __builtin_amdgcn_mfma_f32_16x16x32_f16(ahi[2 * tl + kk], bf, acc2[n], 0, 0, 0);
          else if (t < 8)
            acc2[n] = __builtin_amdgcn_mfma_f32_16x16x32_f16(alo[2 * tl + kk], bf, acc2[n], 0, 0, 0);
          else
            acc[n] = __builtin_amdgcn_mfma_f32_16x16x32_f16(ahi[2 * tl + kk], bf, acc[n], 0, 0, 0);
        }
      }
    }
  }

#pragma unroll
  for (int n = 0; n < 8; ++n) {
    const int ncol = n0 + n * 16 + lj;
    const float bb = bias[ncol];
#pragma unroll
    for (int j = 0; j < 4; ++j) {
      const int tok = m0 + w * 16 + li * 4 + j;
      const float vv = acc[n][j] + acc2[n][j] * LO_INV + bb;
      if (WEXT) {
        const f16 hh = (f16)vv;
        CextOut[(size_t)tok * 512 + ncol] = hh;
        CextOut[(size_t)tok * 512 + 256 + ncol] = (f16)((vv - (float)hh) * LO_SCALE);
      } else {
        Cout[(size_t)tok * Ntot + ncol] = vv;
      }
    }
  }
}

extern "C" void kernel_launch(void* const* d_in, const int* in_sizes, int n_in,
                              void* d_out, int out_size, void* d_ws, size_t ws_size,
                              hipStream_t stream) {
  (void)in_sizes; (void)n_in; (void)out_size; (void)ws_size;
  const float* x     = (const float*)d_in[0];
  const float* W_in  = (const float*)d_in[1];
  const float* b_in  = (const float*)d_in[2];
  const float* W_out = (const float*)d_in[3];
  const float* b_out = (const float*)d_in[4];
  const float* cbs   = (const float*)d_in[5];

  float* out = (float*)d_out;                        // [BT, HIDDEN]
  float* q1  = out + (size_t)BT * HIDDEN;            // [BT, DDIM]
  float* q2  = q1 + (size_t)BT * DDIM;               // [BT, DDIM]
  float* com = q2 + (size_t)BT * DDIM;               // [1]

  f16*   rext      = (f16*)d_ws;                          // [BT][512]   32 MB
  float* qsum      = (float*)(rext + (size_t)BT * 512);   // [BT][256]   32 MB
  f16*   cbext     = (f16*)(qsum + (size_t)BT * DDIM);    // [8192][512]  8 MB
  f16*   W_inext   = cbext + (size_t)NQUANT * KCODE * 512; // [256][1024] 512 KB
  f16*   W_outext  = W_inext + (size_t)DDIM * 1024;        // [512][512]  512 KB
  float* cnorm     = (float*)(W_outext + (size_t)HIDDEN * 512);  // [NQ*K]
  float* commitAcc = cnorm + NQUANT * KCODE;
  unsigned* bar    = (unsigned*)(commitAcc + 1);

  cnorm_kernel<<<NQUANT * KCODE, 256, 0, stream>>>(cbs, cnorm);
  cbext_conv<<<NQUANT * KCODE, 256, 0, stream>>>(cbs, cbext);
  bext_conv<<<(DDIM * HIDDEN + 255) / 256, 256, 0, stream>>>(W_in, W_inext, DDIM, HIDDEN);
  bext_conv<<<(HIDDEN * DDIM + 255) / 256, 256, 0, stream>>>(W_out, W_outext, HIDDEN, DDIM);
  proj3<HIDDEN, true><<<dim3(BT / 128, DDIM / 128), 512, 0, stream>>>(
      x, W_inext, b_in, nullptr, rext, DDIM);
  zero2<<<1, 1, 0, stream>>>(commitAcc, bar);
  rvq_fused7<<<BT / 128, 512, 0, stream>>>(rext, cbext, cbs, cnorm,
                                           qsum, q1, q2, commitAcc, bar);
  proj3<DDIM, false><<<dim3(BT / 128, HIDDEN / 128), 512, 0, stream>>>(
      qsum, W_outext, b_out, out, nullptr, HIDDEN);
  finalize_com<<<1, 1, 0, stream>>>(commitAcc, com);
}

// Round 12
// 745.828 us; speedup vs baseline: 1.6353x; 1.6353x over previous
//
#include <hip/hip_runtime.h>

#define BT     32768
#define HIDDEN 512
#define DDIM   256
#define KCODE  1024
#define NQUANT 8

typedef _Float16 f16;
typedef _Float16 f16x8 __attribute__((ext_vector_type(8)));
typedef float f32x4 __attribute__((ext_vector_type(4)));
typedef float f32x8 __attribute__((ext_vector_type(8)));

#define LO_SCALE 64.0f
#define LO_INV   0.015625f

// ---------------------------------------------------------------------------
// cnorm: ||c||^2 for all NQ*K codes (fp32 exact)
// ---------------------------------------------------------------------------
__global__ __launch_bounds__(256) void cnorm_kernel(const float* __restrict__ cb,
                                                    float* __restrict__ cnorm) {
  __shared__ float red[256];
  const int code = blockIdx.x;
  const float v = cb[(size_t)code * DDIM + threadIdx.x];
  red[threadIdx.x] = v * v;
  __syncthreads();
  for (int s = 128; s > 0; s >>= 1) {
    if (threadIdx.x < s) red[threadIdx.x] += red[threadIdx.x + s];
    __syncthreads();
  }
  if (threadIdx.x == 0) cnorm[code] = red[0];
}

// ---------------------------------------------------------------------------
// codebooks -> f16 hi/lo ext: cbext[c][0..255]=hi, [256..511]=lo*64
// ---------------------------------------------------------------------------
__global__ __launch_bounds__(256) void cbext_conv(const float* __restrict__ cb,
                                                  f16* __restrict__ cbext) {
  const size_t idx = (size_t)blockIdx.x * 256 + threadIdx.x;
  const size_t c = idx >> 8;
  const int d = (int)(idx & 255);
  const float v = cb[idx];
  const f16 hi = (f16)v;
  cbext[c * 512 + d] = hi;
  cbext[c * 512 + 256 + d] = (f16)((v - (float)hi) * LO_SCALE);
}

// ---------------------------------------------------------------------------
// weight -> f16 hi/lo ext: Wext[n][0..K-1]=hi, [K..2K-1]=lo*64
// ---------------------------------------------------------------------------
__global__ __launch_bounds__(256) void bext_conv(const float* __restrict__ W,
                                                 f16* __restrict__ Wext,
                                                 int N, int K) {
  const int idx = blockIdx.x * 256 + threadIdx.x;
  if (idx >= N * K) return;
  const int n = idx / K, k = idx - n * K;
  const float v = W[idx];
  const f16 hi = (f16)v;
  Wext[(size_t)n * 2 * K + k] = hi;
  Wext[(size_t)n * 2 * K + K + k] = (f16)((v - (float)hi) * LO_SCALE);
}

__global__ void zero2(float* commitAcc, unsigned* bar) {
  commitAcc[0] = 0.f;
  bar[0] = 0u;
}

__global__ void finalize_com(const float* __restrict__ a, float* __restrict__ o) {
  o[0] = a[0] * (1.0f / (float)((size_t)NQUANT * BT * DDIM));
}

// ---------------------------------------------------------------------------
// Bounded-spin grid phase barrier (cache-phasing only; timeout-safe).
// ---------------------------------------------------------------------------
__device__ __forceinline__ void phase_barrier(unsigned* bar, unsigned gen,
                                              unsigned nblk) {
  __syncthreads();
  if (threadIdx.x == 0) {
    __threadfence();
    atomicAdd(bar, 1u);
    const unsigned target = gen * nblk;
    int spins = 0;
    while (__hip_atomic_load(bar, __ATOMIC_RELAXED, __HIP_MEMORY_SCOPE_AGENT) < target &&
           spins < 16384) {
      ++spins;
      __builtin_amdgcn_s_sleep(4);
    }
  }
  __syncthreads();
}

// ---------------------------------------------------------------------------
// Fused 8-step RVQ, M=32/wave at 256 threads (4 waves) — the untested cell:
// every 512-thread kernel got VGPR-capped at 128 (4 rounds of evidence);
// 256-thread blocks historically got honest allocation. 1 block/CU (128 KB
// LDS) -> 1 wave/SIMD -> 512-VGPR budget; live set ~210.
// Wave w owns 32 tokens [m0+w*32, +32) in af[2][16] (128 VGPR) and sweeps
// ALL 1024 codes in 16 chunks of 64 (B-fragment feeds 2 m-tiles -> per-CU
// LDS reads HALF of R9). Staging/sweep/argmin/update arithmetic is
// bit-identical to R9 (same chunk geometry, chain order). No wc-split.
// ---------------------------------------------------------------------------
__global__ __launch_bounds__(256, 1) void rvq_fused8(
    const f16* __restrict__ rext, const f16* __restrict__ cbext,
    const float* __restrict__ cbf32, const float* __restrict__ cnorm,
    float* __restrict__ qsum, float* __restrict__ q1, float* __restrict__ q2,
    float* __restrict__ commitAcc, unsigned* __restrict__ bar) {
  __shared__ __align__(16) f16 Bs[2][64][512];   // 128 KB
  __shared__ float redc[256];
  const int tid = threadIdx.x;
  const int w = tid >> 6, l = tid & 63;          // w = 0..3
  const int lj = l & 15, li = l >> 4;
  const int m0 = blockIdx.x * 128;
  const int key = (lj & 7) << 4;                 // read-side swizzle key

  // residual: af[m][s], token row = m0 + w*32 + m*16 + lj (hi 0-7, lo 8-15)
  f16x8 af[2][16];
#pragma unroll
  for (int m = 0; m < 2; ++m) {
    const int row = m0 + w * 32 + m * 16 + lj;
#pragma unroll
    for (int s = 0; s < 16; ++s)
      af[m][s] = *(const f16x8*)&rext[(size_t)row * 512 + s * 32 + li * 8];
  }

  float csum = 0.f;

#pragma unroll 1
  for (int nq = 0; nq < NQUANT; ++nq) {
    if (nq > 0) phase_barrier(bar, (unsigned)nq, gridDim.x);
    const f16* cbq = cbext + (size_t)nq * KCODE * 512;
    const float* cnq = cnorm + nq * KCODE;

    // stage chunk c: LDS row r (0..63) <- code c*64 + r (1 KB, swizzled src)
    auto STAGE = [&](int chunk, int buf) {
#pragma unroll
      for (int q = 0; q < 16; ++q) {
        const int r = w * 16 + q;
        const int code = chunk * 64 + r;
        const char* src = (const char*)(cbq + ((size_t)code << 9)) +
                          ((l * 16) ^ ((r & 7) << 4));
        __builtin_amdgcn_global_load_lds(
            (const __attribute__((address_space(1))) void*)src,
            (__attribute__((address_space(3))) void*)&Bs[buf][r][0], 16, 0, 0);
      }
    };

    float bval[2][4]; int bidxr[2][4];
#pragma unroll
    for (int m = 0; m < 2; ++m)
#pragma unroll
      for (int j = 0; j < 4; ++j) { bval[m][j] = 3.0e38f; bidxr[m][j] = 0; }

    STAGE(0, 0);
    __syncthreads();
    int buf = 0;

#pragma unroll 1
    for (int c = 0; c < 16; ++c) {
      if (c < 15) STAGE(c + 1, buf ^ 1);
      f32x4 acc[2][4];
#pragma unroll
      for (int m = 0; m < 2; ++m)
#pragma unroll
        for (int n = 0; n < 4; ++n) acc[m][n] = (f32x4){0.f, 0.f, 0.f, 0.f};

#pragma unroll
      for (int t = 0; t < 12; ++t) {
        const int tl = (t < 4) ? t : (t < 8 ? t - 4 : t - 8);
        const int roff = (t < 4) ? 512 : 0;      // lo_c | hi_c | hi_c
        const int abase = (t >= 4 && t < 8) ? (8 + 2 * tl) : (2 * tl);
#pragma unroll
        for (int n = 0; n < 4; ++n) {
          const int rr = n * 16 + lj;
          f16x8 bf[2];
#pragma unroll
          for (int kk = 0; kk < 2; ++kk) {
            const int boff = roff + tl * 128 + kk * 64 + li * 16;
            bf[kk] = *(const f16x8*)((const char*)&Bs[buf][rr][0] + (boff ^ key));
          }
#pragma unroll
          for (int m = 0; m < 2; ++m)
#pragma unroll
            for (int kk = 0; kk < 2; ++kk)
              acc[m][n] = __builtin_amdgcn_mfma_f32_16x16x32_f16(
                  af[m][abase + kk], bf[kk], acc[m][n], 0, 0, 0);
        }
        if (t == 7) {
#pragma unroll
          for (int m = 0; m < 2; ++m)
#pragma unroll
            for (int n = 0; n < 4; ++n)
#pragma unroll
              for (int j = 0; j < 4; ++j) acc[m][n][j] *= LO_INV;
        }
      }
      // distances + running argmin (ascending order -> first-occurrence)
#pragma unroll
      for (int n = 0; n < 4; ++n) {
        const int cl = c * 64 + n * 16 + lj;
        const float cn = cnq[cl];
#pragma unroll
        for (int m = 0; m < 2; ++m)
#pragma unroll
          for (int j = 0; j < 4; ++j) {
            const float d = cn - 2.0f * acc[m][n][j];
            if (d < bval[m][j]) { bval[m][j] = d; bidxr[m][j] = cl; }
          }
      }
      __syncthreads();                           // staging + buf reads done
      buf ^= 1;
    }

    // reduce over the 16-lane code axis (lexicographic (val, idx) min)
#pragma unroll
    for (int off = 1; off < 16; off <<= 1) {
#pragma unroll
      for (int m = 0; m < 2; ++m)
#pragma unroll
        for (int j = 0; j < 4; ++j) {
          const float ov = __shfl_xor(bval[m][j], off);
          const int oi = __shfl_xor(bidxr[m][j], off);
          if (ov < bval[m][j] || (ov == bval[m][j] && oi < bidxr[m][j])) {
            bval[m][j] = ov; bidxr[m][j] = oi;
          }
        }
    }
    // broadcast (R9-proven): token t16's code lives in lanes li==t16>>2,
    // register t16&3. This lane updates token t16 = lj, for each m.
    const int src = (lj >> 2) * 16;
    const int sel = lj & 3;
#pragma unroll
    for (int m = 0; m < 2; ++m) {
      const int c0 = __shfl(bidxr[m][0], src);
      const int c1 = __shfl(bidxr[m][1], src);
      const int c2 = __shfl(bidxr[m][2], src);
      const int c3 = __shfl(bidxr[m][3], src);
      const int myCode = (sel == 0) ? c0 : (sel == 1) ? c1 : (sel == 2) ? c2 : c3;

      // in-register residual update + q1/q2 emission (exact f32 code row)
      const int row = m0 + w * 32 + m * 16 + lj;
      const float* qrow = cbf32 + ((size_t)nq * KCODE + myCode) * DDIM;
#pragma unroll
      for (int s = 0; s < 8; ++s) {
        const f32x8 qv = *(const f32x8*)&qrow[s * 32 + li * 8];
        f16x8 h = af[m][s], lo = af[m][8 + s];
#pragma unroll
        for (int i = 0; i < 8; ++i) {
          const float rold = (float)h[i] + (float)lo[i] * LO_INV;
          const float diff = qv[i] - rold;
          csum += diff * diff;
          const float rnew = rold - qv[i];
          const f16 nh = (f16)rnew;
          h[i] = nh;
          lo[i] = (f16)((rnew - (float)nh) * LO_SCALE);
        }
        af[m][s] = h; af[m][8 + s] = lo;
        if (nq == 0)
          *(f32x8*)&q1[(size_t)row * DDIM + s * 32 + li * 8] = qv;
        if (nq == 1)
          *(f32x8*)&q2[(size_t)row * DDIM + s * 32 + li * 8] = qv;
      }
    }
  }

  // qsum = h - r_final (h re-read from untouched rext)
#pragma unroll
  for (int m = 0; m < 2; ++m) {
    const int row = m0 + w * 32 + m * 16 + lj;
#pragma unroll
    for (int s = 0; s < 8; ++s) {
      const f16x8 hh = *(const f16x8*)&rext[(size_t)row * 512 + s * 32 + li * 8];
      const f16x8 hl = *(const f16x8*)&rext[(size_t)row * 512 + 256 + s * 32 + li * 8];
      f32x8 o;
#pragma unroll
      for (int i = 0; i < 8; ++i)
        o[i] = ((float)hh[i] + (float)hl[i] * LO_INV) -
               ((float)af[m][s][i] + (float)af[m][8 + s][i] * LO_INV);
      *(f32x8*)&qsum[(size_t)row * DDIM + s * 32 + li * 8] = o;
    }
  }

  redc[tid] = csum;
  __syncthreads();
  for (int s = 128; s > 0; s >>= 1) {
    if (tid < s) redc[tid] += redc[tid + s];
    __syncthreads();
  }
  if (tid == 0) atomicAdd(commitAcc, redc[0]);
}

// ---------------------------------------------------------------------------
// Projection v3 (builtin MFMA — R9-bench-passing version, unchanged).
// Block = 128 tokens x 128 cols, 8 waves x 16 tokens; B panel in LDS.
// ---------------------------------------------------------------------------
template <int K, bool WEXT>
__global__ __launch_bounds__(512) void proj3(
    const float* __restrict__ A, const f16* __restrict__ Bext,
    const float* __restrict__ bias, float* __restrict__ Cout,
    f16* __restrict__ CextOut, int Ntot) {
  __shared__ __align__(16) f16 Bs[128][512];     // 128 KB
  const int tid = threadIdx.x;
  const int w = tid >> 6, l = tid & 63;
  const int lj = l & 15, li = l >> 4;
  const int m0 = blockIdx.x * 128;
  const int n0 = blockIdx.y * 128;
  const int row_t = m0 + w * 16 + lj;
  const int key = (lj & 7) << 4;

  f32x4 acc[8], acc2[8];
#pragma unroll
  for (int n = 0; n < 8; ++n) {
    acc[n] = (f32x4){0.f, 0.f, 0.f, 0.f};
    acc2[n] = (f32x4){0.f, 0.f, 0.f, 0.f};
  }

#pragma unroll 1
  for (int p = 0; p < K / 256; ++p) {
    __syncthreads();
#pragma unroll
    for (int q = 0; q < 16; ++q) {
      const int r = w * 16 + q;
      const int nrow = n0 + r;
      const int byteoff = (l * 16) ^ ((r & 7) << 4);
      const char* hi_base =
          (const char*)Bext + ((size_t)nrow * 2 * K + p * 256) * 2;
      const char* lo_base =
          (const char*)Bext + ((size_t)nrow * 2 * K + K + p * 256) * 2;
      const char* src = (byteoff < 512) ? hi_base + byteoff
                                        : lo_base + (byteoff - 512);
      __builtin_amdgcn_global_load_lds(
          (const __attribute__((address_space(1))) void*)src,
          (__attribute__((address_space(3))) void*)&Bs[r][0], 16, 0, 0);
    }
    f16x8 ahi[8], alo[8];
#pragma unroll
    for (int s = 0; s < 8; ++s) {
      const f32x8 v = *(const f32x8*)&A[(size_t)row_t * K + p * 256 + s * 32 + li * 8];
      f16x8 h, lo;
#pragma unroll
      for (int i = 0; i < 8; ++i) {
        const f16 hh = (f16)v[i];
        h[i] = hh;
        lo[i] = (f16)((v[i] - (float)hh) * LO_SCALE);
      }
      ahi[s] = h; alo[s] = lo;
    }
    __syncthreads();

#pragma unroll
    for (int t = 0; t < 12; ++t) {
      const int tl = (t < 4) ? t : (t < 8 ? t - 4 : t - 8);
      const int roff = (t < 4) ? 512 : 0;
#pragma unroll
      for (int n = 0; n < 8; ++n) {
        const int rr = n * 16 + lj;
#pragma unroll
        for (int kk = 0; kk < 2; ++kk) {
          const int boff = roff + tl * 128 + kk * 64 + li * 16;
          const f16x8 bf = *(const f16x8*)((const char*)&Bs[rr][0] + (boff ^ key));
          if (t < 4)
            acc2[n] = __builtin_amdgcn_mfma_f32_16x16x32_f16(ahi[2 * tl + kk], bf, acc2[n], 0, 0, 0);
          else if (t < 8)
            acc2[n] = __builtin_amdgcn_mfma_f32_16x16x32_f16(alo[2 * tl + kk], bf, acc2[n], 0, 0, 0);
          else
            acc[n] = __builtin_amdgcn_mfma_f32_16x16x32_f16(ahi[2 * tl + kk], bf, acc[n], 0, 0, 0);
        }
      }
    }
  }

#pragma unroll
  for (int n = 0; n < 8; ++n) {
    const int ncol = n0 + n * 16 + lj;
    const float bb = bias[ncol];
#pragma unroll
    for (int j = 0; j < 4; ++j) {
      const int tok = m0 + w * 16 + li * 4 + j;
      const float vv = acc[n][j] + acc2[n][j] * LO_INV + bb;
      if (WEXT) {
        const f16 hh = (f16)vv;
        CextOut[(size_t)tok * 512 + ncol] = hh;
        CextOut[(size_t)tok * 512 + 256 + ncol] = (f16)((vv - (float)hh) * LO_SCALE);
      } else {
        Cout[(size_t)tok * Ntot + ncol] = vv;
      }
    }
  }
}

extern "C" void kernel_launch(void* const* d_in, const int* in_sizes, int n_in,
                              void* d_out, int out_size, void* d_ws, size_t ws_size,
                              hipStream_t stream) {
  (void)in_sizes; (void)n_in; (void)out_size; (void)ws_size;
  const float* x     = (const float*)d_in[0];
  const float* W_in  = (const float*)d_in[1];
  const float* b_in  = (const float*)d_in[2];
  const float* W_out = (const float*)d_in[3];
  const float* b_out = (const float*)d_in[4];
  const float* cbs   = (const float*)d_in[5];

  float* out = (float*)d_out;                        // [BT, HIDDEN]
  float* q1  = out + (size_t)BT * HIDDEN;            // [BT, DDIM]
  float* q2  = q1 + (size_t)BT * DDIM;               // [BT, DDIM]
  float* com = q2 + (size_t)BT * DDIM;               // [1]

  f16*   rext      = (f16*)d_ws;                          // [BT][512]   32 MB
  float* qsum      = (float*)(rext + (size_t)BT * 512);   // [BT][256]   32 MB
  f16*   cbext     = (f16*)(qsum + (size_t)BT * DDIM);    // [8192][512]  8 MB
  f16*   W_inext   = cbext + (size_t)NQUANT * KCODE * 512; // [256][1024] 512 KB
  f16*   W_outext  = W_inext + (size_t)DDIM * 1024;        // [512][512]  512 KB
  float* cnorm     = (float*)(W_outext + (size_t)HIDDEN * 512);  // [NQ*K]
  float* commitAcc = cnorm + NQUANT * KCODE;
  unsigned* bar    = (unsigned*)(commitAcc + 1);

  cnorm_kernel<<<NQUANT * KCODE, 256, 0, stream>>>(cbs, cnorm);
  cbext_conv<<<NQUANT * KCODE, 256, 0, stream>>>(cbs, cbext);
  bext_conv<<<(DDIM * HIDDEN + 255) / 256, 256, 0, stream>>>(W_in, W_inext, DDIM, HIDDEN);
  bext_conv<<<(HIDDEN * DDIM + 255) / 256, 256, 0, stream>>>(W_out, W_outext, HIDDEN, DDIM);
  proj3<HIDDEN, true><<<dim3(BT / 128, DDIM / 128), 512, 0, stream>>>(
      x, W_inext, b_in, nullptr, rext, DDIM);
  zero2<<<1, 1, 0, stream>>>(commitAcc, bar);
  rvq_fused8<<<BT / 128, 256, 0, stream>>>(rext, cbext, cbs, cnorm,
                                           qsum, q1, q2, commitAcc, bar);
  proj3<DDIM, false><<<dim3(BT / 128, HIDDEN / 128), 512, 0, stream>>>(
      qsum, W_outext, b_out, out, nullptr, HIDDEN);
  finalize_com<<<1, 1, 0, stream>>>(commitAcc, com);
}

// Round 13
// 730.907 us; speedup vs baseline: 1.6687x; 1.0204x over previous
//
#include <hip/hip_runtime.h>

#define BT     32768
#define HIDDEN 512
#define DDIM   256
#define KCODE  1024
#define NQUANT 8

typedef _Float16 f16;
typedef _Float16 f16x8 __attribute__((ext_vector_type(8)));
typedef float f32x4 __attribute__((ext_vector_type(4)));
typedef float f32x8 __attribute__((ext_vector_type(8)));

#define LO_SCALE 64.0f
#define LO_INV   0.015625f

// ---------------------------------------------------------------------------
// cnorm: ||c||^2 for all NQ*K codes (fp32 exact)
// ---------------------------------------------------------------------------
__global__ __launch_bounds__(256) void cnorm_kernel(const float* __restrict__ cb,
                                                    float* __restrict__ cnorm) {
  __shared__ float red[256];
  const int code = blockIdx.x;
  const float v = cb[(size_t)code * DDIM + threadIdx.x];
  red[threadIdx.x] = v * v;
  __syncthreads();
  for (int s = 128; s > 0; s >>= 1) {
    if (threadIdx.x < s) red[threadIdx.x] += red[threadIdx.x + s];
    __syncthreads();
  }
  if (threadIdx.x == 0) cnorm[code] = red[0];
}

// ---------------------------------------------------------------------------
// codebooks -> f16 hi/lo ext: cbext[c][0..255]=hi, [256..511]=lo*64
// ---------------------------------------------------------------------------
__global__ __launch_bounds__(256) void cbext_conv(const float* __restrict__ cb,
                                                  f16* __restrict__ cbext) {
  const size_t idx = (size_t)blockIdx.x * 256 + threadIdx.x;
  const size_t c = idx >> 8;
  const int d = (int)(idx & 255);
  const float v = cb[idx];
  const f16 hi = (f16)v;
  cbext[c * 512 + d] = hi;
  cbext[c * 512 + 256 + d] = (f16)((v - (float)hi) * LO_SCALE);
}

// ---------------------------------------------------------------------------
// weight -> f16 hi/lo ext: Wext[n][0..K-1]=hi, [K..2K-1]=lo*64
// ---------------------------------------------------------------------------
__global__ __launch_bounds__(256) void bext_conv(const float* __restrict__ W,
                                                 f16* __restrict__ Wext,
                                                 int N, int K) {
  const int idx = blockIdx.x * 256 + threadIdx.x;
  if (idx >= N * K) return;
  const int n = idx / K, k = idx - n * K;
  const float v = W[idx];
  const f16 hi = (f16)v;
  Wext[(size_t)n * 2 * K + k] = hi;
  Wext[(size_t)n * 2 * K + K + k] = (f16)((v - (float)hi) * LO_SCALE);
}

__global__ void zero2(float* commitAcc, unsigned* bar) {
  commitAcc[0] = 0.f;
  bar[0] = 0u;
}

__global__ void finalize_com(const float* __restrict__ a, float* __restrict__ o) {
  o[0] = a[0] * (1.0f / (float)((size_t)NQUANT * BT * DDIM));
}

// ---------------------------------------------------------------------------
// Bounded-spin grid phase barrier (cache-phasing only; timeout-safe).
// ---------------------------------------------------------------------------
__device__ __forceinline__ void phase_barrier(unsigned* bar, unsigned gen,
                                              unsigned nblk) {
  __syncthreads();
  if (threadIdx.x == 0) {
    __threadfence();
    atomicAdd(bar, 1u);
    const unsigned target = gen * nblk;
    int spins = 0;
    while (__hip_atomic_load(bar, __ATOMIC_RELAXED, __HIP_MEMORY_SCOPE_AGENT) < target &&
           spins < 16384) {
      ++spins;
      __builtin_amdgcn_s_sleep(4);
    }
  }
  __syncthreads();
}

// ---------------------------------------------------------------------------
// Fused 8-step RVQ v9: R12 structure (256 thr, 4 waves, M=32/wave, 208 VGPR
// no-spill) + shared-hi_c restructure: split accumulators accM (hi*hi) and
// accC (cross, x64) so each hi_c LDS read feeds 4 MFMAs (lo_r*hi_c -> accC,
// hi_r*hi_c -> accM, both m). ds_reads/chunk/wave: 96 -> 64 (-33%).
// distance = cnorm - 2*(accM + accC/64).
// ---------------------------------------------------------------------------
__global__ __launch_bounds__(256, 1) void rvq_fused9(
    const f16* __restrict__ rext, const f16* __restrict__ cbext,
    const float* __restrict__ cbf32, const float* __restrict__ cnorm,
    float* __restrict__ qsum, float* __restrict__ q1, float* __restrict__ q2,
    float* __restrict__ commitAcc, unsigned* __restrict__ bar) {
  __shared__ __align__(16) f16 Bs[2][64][512];   // 128 KB
  __shared__ float redc[256];
  const int tid = threadIdx.x;
  const int w = tid >> 6, l = tid & 63;          // w = 0..3
  const int lj = l & 15, li = l >> 4;
  const int m0 = blockIdx.x * 128;
  const int key = (lj & 7) << 4;                 // read-side swizzle key

  // residual: af[m][s], token row = m0 + w*32 + m*16 + lj (hi 0-7, lo 8-15)
  f16x8 af[2][16];
#pragma unroll
  for (int m = 0; m < 2; ++m) {
    const int row = m0 + w * 32 + m * 16 + lj;
#pragma unroll
    for (int s = 0; s < 16; ++s)
      af[m][s] = *(const f16x8*)&rext[(size_t)row * 512 + s * 32 + li * 8];
  }

  float csum = 0.f;

#pragma unroll 1
  for (int nq = 0; nq < NQUANT; ++nq) {
    if (nq > 0) phase_barrier(bar, (unsigned)nq, gridDim.x);
    const f16* cbq = cbext + (size_t)nq * KCODE * 512;
    const float* cnq = cnorm + nq * KCODE;

    // stage chunk c: LDS row r (0..63) <- code c*64 + r (1 KB, swizzled src)
    auto STAGE = [&](int chunk, int buf) {
#pragma unroll
      for (int q = 0; q < 16; ++q) {
        const int r = w * 16 + q;
        const int code = chunk * 64 + r;
        const char* src = (const char*)(cbq + ((size_t)code << 9)) +
                          ((l * 16) ^ ((r & 7) << 4));
        __builtin_amdgcn_global_load_lds(
            (const __attribute__((address_space(1))) void*)src,
            (__attribute__((address_space(3))) void*)&Bs[buf][r][0], 16, 0, 0);
      }
    };

    float bval[2][4]; int bidxr[2][4];
#pragma unroll
    for (int m = 0; m < 2; ++m)
#pragma unroll
      for (int j = 0; j < 4; ++j) { bval[m][j] = 3.0e38f; bidxr[m][j] = 0; }

    STAGE(0, 0);
    __syncthreads();
    int buf = 0;

#pragma unroll 1
    for (int c = 0; c < 16; ++c) {
      if (c < 15) STAGE(c + 1, buf ^ 1);
      f32x4 accM[2][4], accC[2][4];
#pragma unroll
      for (int m = 0; m < 2; ++m)
#pragma unroll
        for (int n = 0; n < 4; ++n) {
          accM[m][n] = (f32x4){0.f, 0.f, 0.f, 0.f};
          accC[m][n] = (f32x4){0.f, 0.f, 0.f, 0.f};
        }

      // phase 1 (t 0..3): lo_c reads -> hi_r * lo_c into accC
#pragma unroll
      for (int tl = 0; tl < 4; ++tl) {
#pragma unroll
        for (int n = 0; n < 4; ++n) {
          const int rr = n * 16 + lj;
          f16x8 bf[2];
#pragma unroll
          for (int kk = 0; kk < 2; ++kk) {
            const int boff = 512 + tl * 128 + kk * 64 + li * 16;
            bf[kk] = *(const f16x8*)((const char*)&Bs[buf][rr][0] + (boff ^ key));
          }
#pragma unroll
          for (int m = 0; m < 2; ++m)
#pragma unroll
            for (int kk = 0; kk < 2; ++kk)
              accC[m][n] = __builtin_amdgcn_mfma_f32_16x16x32_f16(
                  af[m][2 * tl + kk], bf[kk], accC[m][n], 0, 0, 0);
        }
      }
      // phase 2 (t 4..7): hi_c reads shared -> lo_r*hi_c (accC) AND
      // hi_r*hi_c (accM), both m: 4 MFMAs per ds_read.
#pragma unroll
      for (int tl = 0; tl < 4; ++tl) {
#pragma unroll
        for (int n = 0; n < 4; ++n) {
          const int rr = n * 16 + lj;
          f16x8 bf[2];
#pragma unroll
          for (int kk = 0; kk < 2; ++kk) {
            const int boff = tl * 128 + kk * 64 + li * 16;
            bf[kk] = *(const f16x8*)((const char*)&Bs[buf][rr][0] + (boff ^ key));
          }
#pragma unroll
          for (int m = 0; m < 2; ++m)
#pragma unroll
            for (int kk = 0; kk < 2; ++kk) {
              accC[m][n] = __builtin_amdgcn_mfma_f32_16x16x32_f16(
                  af[m][8 + 2 * tl + kk], bf[kk], accC[m][n], 0, 0, 0);
              accM[m][n] = __builtin_amdgcn_mfma_f32_16x16x32_f16(
                  af[m][2 * tl + kk], bf[kk], accM[m][n], 0, 0, 0);
            }
        }
      }
      // distances + running argmin (ascending order -> first-occurrence)
#pragma unroll
      for (int n = 0; n < 4; ++n) {
        const int cl = c * 64 + n * 16 + lj;
        const float cn = cnq[cl];
#pragma unroll
        for (int m = 0; m < 2; ++m)
#pragma unroll
          for (int j = 0; j < 4; ++j) {
            const float d = cn - 2.0f * (accM[m][n][j] + accC[m][n][j] * LO_INV);
            if (d < bval[m][j]) { bval[m][j] = d; bidxr[m][j] = cl; }
          }
      }
      __syncthreads();                           // staging + buf reads done
      buf ^= 1;
    }

    // reduce over the 16-lane code axis (lexicographic (val, idx) min)
#pragma unroll
    for (int off = 1; off < 16; off <<= 1) {
#pragma unroll
      for (int m = 0; m < 2; ++m)
#pragma unroll
        for (int j = 0; j < 4; ++j) {
          const float ov = __shfl_xor(bval[m][j], off);
          const int oi = __shfl_xor(bidxr[m][j], off);
          if (ov < bval[m][j] || (ov == bval[m][j] && oi < bidxr[m][j])) {
            bval[m][j] = ov; bidxr[m][j] = oi;
          }
        }
    }
    // broadcast (R9/R12-proven): token t16's code lives in lanes li==t16>>2,
    // register t16&3. This lane updates token t16 = lj, for each m.
    const int src = (lj >> 2) * 16;
    const int sel = lj & 3;
#pragma unroll
    for (int m = 0; m < 2; ++m) {
      const int c0 = __shfl(bidxr[m][0], src);
      const int c1 = __shfl(bidxr[m][1], src);
      const int c2 = __shfl(bidxr[m][2], src);
      const int c3 = __shfl(bidxr[m][3], src);
      const int myCode = (sel == 0) ? c0 : (sel == 1) ? c1 : (sel == 2) ? c2 : c3;

      // in-register residual update + q1/q2 emission (exact f32 code row)
      const int row = m0 + w * 32 + m * 16 + lj;
      const float* qrow = cbf32 + ((size_t)nq * KCODE + myCode) * DDIM;
#pragma unroll
      for (int s = 0; s < 8; ++s) {
        const f32x8 qv = *(const f32x8*)&qrow[s * 32 + li * 8];
        f16x8 h = af[m][s], lo = af[m][8 + s];
#pragma unroll
        for (int i = 0; i < 8; ++i) {
          const float rold = (float)h[i] + (float)lo[i] * LO_INV;
          const float diff = qv[i] - rold;
          csum += diff * diff;
          const float rnew = rold - qv[i];
          const f16 nh = (f16)rnew;
          h[i] = nh;
          lo[i] = (f16)((rnew - (float)nh) * LO_SCALE);
        }
        af[m][s] = h; af[m][8 + s] = lo;
        if (nq == 0)
          *(f32x8*)&q1[(size_t)row * DDIM + s * 32 + li * 8] = qv;
        if (nq == 1)
          *(f32x8*)&q2[(size_t)row * DDIM + s * 32 + li * 8] = qv;
      }
    }
  }

  // qsum = h - r_final (h re-read from untouched rext)
#pragma unroll
  for (int m = 0; m < 2; ++m) {
    const int row = m0 + w * 32 + m * 16 + lj;
#pragma unroll
    for (int s = 0; s < 8; ++s) {
      const f16x8 hh = *(const f16x8*)&rext[(size_t)row * 512 + s * 32 + li * 8];
      const f16x8 hl = *(const f16x8*)&rext[(size_t)row * 512 + 256 + s * 32 + li * 8];
      f32x8 o;
#pragma unroll
      for (int i = 0; i < 8; ++i)
        o[i] = ((float)hh[i] + (float)hl[i] * LO_INV) -
               ((float)af[m][s][i] + (float)af[m][8 + s][i] * LO_INV);
      *(f32x8*)&qsum[(size_t)row * DDIM + s * 32 + li * 8] = o;
    }
  }

  redc[tid] = csum;
  __syncthreads();
  for (int s = 128; s > 0; s >>= 1) {
    if (tid < s) redc[tid] += redc[tid + s];
    __syncthreads();
  }
  if (tid == 0) atomicAdd(commitAcc, redc[0]);
}

// ---------------------------------------------------------------------------
// Projection v3 (builtin MFMA — R9/R12-bench-passing version, unchanged).
// Block = 128 tokens x 128 cols, 8 waves x 16 tokens; B panel in LDS.
// ---------------------------------------------------------------------------
template <int K, bool WEXT>
__global__ __launch_bounds__(512) void proj3(
    const float* __restrict__ A, const f16* __restrict__ Bext,
    const float* __restrict__ bias, float* __restrict__ Cout,
    f16* __restrict__ CextOut, int Ntot) {
  __shared__ __align__(16) f16 Bs[128][512];     // 128 KB
  const int tid = threadIdx.x;
  const int w = tid >> 6, l = tid & 63;
  const int lj = l & 15, li = l >> 4;
  const int m0 = blockIdx.x * 128;
  const int n0 = blockIdx.y * 128;
  const int row_t = m0 + w * 16 + lj;
  const int key = (lj & 7) << 4;

  f32x4 acc[8], acc2[8];
#pragma unroll
  for (int n = 0; n < 8; ++n) {
    acc[n] = (f32x4){0.f, 0.f, 0.f, 0.f};
    acc2[n] = (f32x4){0.f, 0.f, 0.f, 0.f};
  }

#pragma unroll 1
  for (int p = 0; p < K / 256; ++p) {
    __syncthreads();
#pragma unroll
    for (int q = 0; q < 16; ++q) {
      const int r = w * 16 + q;
      const int nrow = n0 + r;
      const int byteoff = (l * 16) ^ ((r & 7) << 4);
      const char* hi_base =
          (const char*)Bext + ((size_t)nrow * 2 * K + p * 256) * 2;
      const char* lo_base =
          (const char*)Bext + ((size_t)nrow * 2 * K + K + p * 256) * 2;
      const char* src = (byteoff < 512) ? hi_base + byteoff
                                        : lo_base + (byteoff - 512);
      __builtin_amdgcn_global_load_lds(
          (const __attribute__((address_space(1))) void*)src,
          (__attribute__((address_space(3))) void*)&Bs[r][0], 16, 0, 0);
    }
    f16x8 ahi[8], alo[8];
#pragma unroll
    for (int s = 0; s < 8; ++s) {
      const f32x8 v = *(const f32x8*)&A[(size_t)row_t * K + p * 256 + s * 32 + li * 8];
      f16x8 h, lo;
#pragma unroll
      for (int i = 0; i < 8; ++i) {
        const f16 hh = (f16)v[i];
        h[i] = hh;
        lo[i] = (f16)((v[i] - (float)hh) * LO_SCALE);
      }
      ahi[s] = h; alo[s] = lo;
    }
    __syncthreads();

#pragma unroll
    for (int t = 0; t < 12; ++t) {
      const int tl = (t < 4) ? t : (t < 8 ? t - 4 : t - 8);
      const int roff = (t < 4) ? 512 : 0;
#pragma unroll
      for (int n = 0; n < 8; ++n) {
        const int rr = n * 16 + lj;
#pragma unroll
        for (int kk = 0; kk < 2; ++kk) {
          const int boff = roff + tl * 128 + kk * 64 + li * 16;
          const f16x8 bf = *(const f16x8*)((const char*)&Bs[rr][0] + (boff ^ key));
          if (t < 4)
            acc2[n] = __builtin_amdgcn_mfma_f32_16x16x32_f16(ahi[2 * tl + kk], bf, acc2[n], 0, 0, 0);
          else if (t < 8)
            acc2[n] = __builtin_amdgcn_mfma_f32_16x16x32_f16(alo[2 * tl + kk], bf, acc2[n], 0, 0, 0);
          else
            acc[n] = __builtin_amdgcn_mfma_f32_16x16x32_f16(ahi[2 * tl + kk], bf, acc[n], 0, 0, 0);
        }
      }
    }
  }

#pragma unroll
  for (int n = 0; n < 8; ++n) {
    const int ncol = n0 + n * 16 + lj;
    const float bb = bias[ncol];
#pragma unroll
    for (int j = 0; j < 4; ++j) {
      const int tok = m0 + w * 16 + li * 4 + j;
      const float vv = acc[n][j] + acc2[n][j] * LO_INV + bb;
      if (WEXT) {
        const f16 hh = (f16)vv;
        CextOut[(size_t)tok * 512 + ncol] = hh;
        CextOut[(size_t)tok * 512 + 256 + ncol] = (f16)((vv - (float)hh) * LO_SCALE);
      } else {
        Cout[(size_t)tok * Ntot + ncol] = vv;
      }
    }
  }
}

extern "C" void kernel_launch(void* const* d_in, const int* in_sizes, int n_in,
                              void* d_out, int out_size, void* d_ws, size_t ws_size,
                              hipStream_t stream) {
  (void)in_sizes; (void)n_in; (void)out_size; (void)ws_size;
  const float* x     = (const float*)d_in[0];
  const float* W_in  = (const float*)d_in[1];
  const float* b_in  = (const float*)d_in[2];
  const float* W_out = (const float*)d_in[3];
  const float* b_out = (const float*)d_in[4];
  const float* cbs   = (const float*)d_in[5];

  float* out = (float*)d_out;                        // [BT, HIDDEN]
  float* q1  = out + (size_t)BT * HIDDEN;            // [BT, DDIM]
  float* q2  = q1 + (size_t)BT * DDIM;               // [BT, DDIM]
  float* com = q2 + (size_t)BT * DDIM;               // [1]

  f16*   rext      = (f16*)d_ws;                          // [BT][512]   32 MB
  float* qsum      = (float*)(rext + (size_t)BT * 512);   // [BT][256]   32 MB
  f16*   cbext     = (f16*)(qsum + (size_t)BT * DDIM);    // [8192][512]  8 MB
  f16*   W_inext   = cbext + (size_t)NQUANT * KCODE * 512; // [256][1024] 512 KB
  f16*   W_outext  = W_inext + (size_t)DDIM * 1024;        // [512][512]  512 KB
  float* cnorm     = (float*)(W_outext + (size_t)HIDDEN * 512);  // [NQ*K]
  float* commitAcc = cnorm + NQUANT * KCODE;
  unsigned* bar    = (unsigned*)(commitAcc + 1);

  cnorm_kernel<<<NQUANT * KCODE, 256, 0, stream>>>(cbs, cnorm);
  cbext_conv<<<NQUANT * KCODE, 256, 0, stream>>>(cbs, cbext);
  bext_conv<<<(DDIM * HIDDEN + 255) / 256, 256, 0, stream>>>(W_in, W_inext, DDIM, HIDDEN);
  bext_conv<<<(HIDDEN * DDIM + 255) / 256, 256, 0, stream>>>(W_out, W_outext, HIDDEN, DDIM);
  proj3<HIDDEN, true><<<dim3(BT / 128, DDIM / 128), 512, 0, stream>>>(
      x, W_inext, b_in, nullptr, rext, DDIM);
  zero2<<<1, 1, 0, stream>>>(commitAcc, bar);
  rvq_fused9<<<BT / 128, 256, 0, stream>>>(rext, cbext, cbs, cnorm,
                                           qsum, q1, q2, commitAcc, bar);
  proj3<DDIM, false><<<dim3(BT / 128, HIDDEN / 128), 512, 0, stream>>>(
      qsum, W_outext, b_out, out, nullptr, HIDDEN);
  finalize_com<<<1, 1, 0, stream>>>(commitAcc, com);
}